// Round 1
// baseline (2252.080 us; speedup 1.0000x reference)
//
#include <hip/hip_runtime.h>
#include <hip/hip_bf16.h>
#include <math.h>

#define D_MODEL 1024
#define NHEAD   16
#define DKH     64
#define BATCH   4
#define SEQ     2048
#define BH      (BATCH*NHEAD)    // 64
#define MROWS   (BATCH*SEQ)      // 8192

// ---------------------------------------------------------------------------
// Kernel A: fused QKV projection (C[m,d] = sum_k X[m,k]*W[d,k]) + RoPE on Q,K.
// Output stored head-major: out[bh][s][c], bh = b*16 + h, c = d & 63.
// fp32 vector-FMA GEMM, 64x64 tile, BK=16, 256 threads, 4x4 per-thread tile.
// ---------------------------------------------------------------------------
__global__ __launch_bounds__(256)
void qkv_rope_kernel(const float* __restrict__ x,
                     const int*   __restrict__ pos,
                     const float* __restrict__ Wq,
                     const float* __restrict__ Wk,
                     const float* __restrict__ Wv,
                     float* __restrict__ qb,
                     float* __restrict__ kb,
                     float* __restrict__ vb)
{
    const int which = blockIdx.z;
    const float* __restrict__ W    = (which==0) ? Wq : (which==1) ? Wk : Wv;
    float*       __restrict__ outb = (which==0) ? qb : (which==1) ? kb : vb;

    __shared__ float As[16][68];   // [k][m], +4 pad keeps rows 16B-aligned
    __shared__ float Bs[16][68];   // [k][n]

    const int t    = threadIdx.x;
    const int m0   = blockIdx.x * 64;
    const int n0   = blockIdx.y * 64;
    const int tx   = t & 15, ty = t >> 4;
    const int lrow = t >> 2;          // 0..63
    const int lk4  = (t & 3) << 2;    // 0,4,8,12

    float acc[4][4];
    #pragma unroll
    for (int i=0;i<4;i++)
        #pragma unroll
        for (int j=0;j<4;j++) acc[i][j]=0.f;

    const float* xp = x + (size_t)(m0 + lrow)*D_MODEL + lk4;
    const float* wp = W + (size_t)(n0 + lrow)*D_MODEL + lk4;

    for (int k0 = 0; k0 < D_MODEL; k0 += 16) {
        float4 xa = *(const float4*)(xp + k0);
        float4 wb = *(const float4*)(wp + k0);
        As[lk4+0][lrow]=xa.x; As[lk4+1][lrow]=xa.y; As[lk4+2][lrow]=xa.z; As[lk4+3][lrow]=xa.w;
        Bs[lk4+0][lrow]=wb.x; Bs[lk4+1][lrow]=wb.y; Bs[lk4+2][lrow]=wb.z; Bs[lk4+3][lrow]=wb.w;
        __syncthreads();
        #pragma unroll
        for (int kk=0;kk<16;kk++){
            float4 a4 = *(const float4*)&As[kk][ty<<2];
            float4 b4 = *(const float4*)&Bs[kk][tx<<2];
            float a[4] = {a4.x,a4.y,a4.z,a4.w};
            float b[4] = {b4.x,b4.y,b4.z,b4.w};
            #pragma unroll
            for (int i=0;i<4;i++)
                #pragma unroll
                for (int j=0;j<4;j++) acc[i][j] = fmaf(a[i], b[j], acc[i][j]);
        }
        __syncthreads();
    }

    // Epilogue: RoPE (Q,K only) + head-major store.
    const int d0 = n0 + (tx<<2);
    const int h  = d0 >> 6;
    const int c0 = d0 & 63;
    #pragma unroll
    for (int i=0;i<4;i++){
        const int m = m0 + (ty<<2) + i;
        const int b = m >> 11;          // /2048 (block never crosses batch)
        const int s = m & 2047;
        float o0 = acc[i][0], o1 = acc[i][1], o2 = acc[i][2], o3 = acc[i][3];
        if (which < 2) {
            const float p = (float)pos[s];
            // pair 0: cols (c0, c0+1), pair index jj0 = c0/2
            {
                const int   jj  = c0 >> 1;
                const float invf = powf(10000.0f, -(float)jj * (1.0f/32.0f));
                const float ang  = p * invf;
                float sn, cs; sincosf(ang, &sn, &cs);
                float xe = o0, xo = o1;
                o0 = xe*cs - xo*sn;
                o1 = xe*sn + xo*cs;
            }
            // pair 1: cols (c0+2, c0+3), pair index jj0+1
            {
                const int   jj  = (c0 >> 1) + 1;
                const float invf = powf(10000.0f, -(float)jj * (1.0f/32.0f));
                const float ang  = p * invf;
                float sn, cs; sincosf(ang, &sn, &cs);
                float xe = o2, xo = o3;
                o2 = xe*cs - xo*sn;
                o3 = xe*sn + xo*cs;
            }
        }
        float4 ov = {o0,o1,o2,o3};
        *(float4*)&outb[(((size_t)(b*NHEAD + h))*SEQ + s)*DKH + c0] = ov;
    }
}

// ---------------------------------------------------------------------------
// Kernel B: causal flash attention, one 64-row Q tile per block, 64 heads.
// fp32 vector compute. Q/K stored d-major in LDS (transposed on load) so the
// QK^T inner loop reads contiguous float4s; V row-major; P c-major.
// Online softmax state (m,l) replicated across the 16 lanes of each row group.
// Writes output IN PLACE over the Q buffer (each block owns its Q rows).
// ---------------------------------------------------------------------------
__global__ __launch_bounds__(256)
void flash_kernel(const float* __restrict__ qb,
                  const float* __restrict__ kb,
                  const float* __restrict__ vb,
                  float* __restrict__ ob)
{
    const int qt = blockIdx.x;    // 0..31
    const int bh = blockIdx.y;    // 0..63
    const float* Q = qb + ((size_t)bh*SEQ + (size_t)qt*64)*DKH;
    const float* K = kb + (size_t)bh*SEQ*DKH;
    const float* V = vb + (size_t)bh*SEQ*DKH;

    __shared__ float Qst[64][68];  // [d][r]
    __shared__ float Kst[64][68];  // [d][c]
    __shared__ float Vs [64][68];  // [c][d]
    __shared__ float Pst[64][68];  // [c][r]

    const int t  = threadIdx.x;
    const int tx = t & 15, ty = t >> 4;

    // Load Q tile, transposed into [d][r].
    #pragma unroll
    for (int rep=0; rep<4; rep++){
        int idx = rep*256 + t;
        int r   = idx >> 4;
        int c4  = (idx & 15) << 2;
        float4 qv = *(const float4*)&Q[(size_t)r*DKH + c4];
        Qst[c4+0][r]=qv.x; Qst[c4+1][r]=qv.y; Qst[c4+2][r]=qv.z; Qst[c4+3][r]=qv.w;
    }

    float Oacc[4][4];
    float mrow[4], lsum[4];
    #pragma unroll
    for (int i=0;i<4;i++){
        mrow[i] = -1.0e30f; lsum[i] = 0.f;
        #pragma unroll
        for (int j=0;j<4;j++) Oacc[i][j]=0.f;
    }

    for (int kt=0; kt<=qt; kt++){
        __syncthreads();  // previous iteration's readers of Kst/Vs/Pst done (covers Qst store on iter 0)
        #pragma unroll
        for (int rep=0; rep<4; rep++){
            int idx = rep*256 + t;
            int r   = idx >> 4;
            int c4  = (idx & 15) << 2;
            float4 kv = *(const float4*)&K[((size_t)kt*64 + r)*DKH + c4];
            Kst[c4+0][r]=kv.x; Kst[c4+1][r]=kv.y; Kst[c4+2][r]=kv.z; Kst[c4+3][r]=kv.w;
            float4 vv = *(const float4*)&V[((size_t)kt*64 + r)*DKH + c4];
            *(float4*)&Vs[r][c4] = vv;
        }
        __syncthreads();

        // ---- scores: S = Q K^T * 1/8 ----
        float sc[4][4];
        #pragma unroll
        for (int i=0;i<4;i++)
            #pragma unroll
            for (int j=0;j<4;j++) sc[i][j]=0.f;
        for (int kk=0; kk<64; kk++){
            float4 a4 = *(const float4*)&Qst[kk][ty<<2];
            float4 b4 = *(const float4*)&Kst[kk][tx<<2];
            float a[4] = {a4.x,a4.y,a4.z,a4.w};
            float b[4] = {b4.x,b4.y,b4.z,b4.w};
            #pragma unroll
            for (int i=0;i<4;i++)
                #pragma unroll
                for (int j=0;j<4;j++) sc[i][j] = fmaf(a[i], b[j], sc[i][j]);
        }
        const float scale = 0.125f;  // 1/sqrt(64)
        #pragma unroll
        for (int i=0;i<4;i++)
            #pragma unroll
            for (int j=0;j<4;j++) sc[i][j] *= scale;
        if (kt == qt) {
            #pragma unroll
            for (int i=0;i<4;i++){
                const int rg = qt*64 + (ty<<2) + i;
                #pragma unroll
                for (int j=0;j<4;j++){
                    const int cg = kt*64 + (tx<<2) + j;
                    if (cg > rg) sc[i][j] = -1.0e30f;
                }
            }
        }

        // ---- online softmax (row state replicated across the 16 tx lanes) ----
        #pragma unroll
        for (int i=0;i<4;i++){
            float rm = fmaxf(fmaxf(sc[i][0],sc[i][1]), fmaxf(sc[i][2],sc[i][3]));
            #pragma unroll
            for (int msk=1; msk<16; msk<<=1) rm = fmaxf(rm, __shfl_xor(rm, msk));
            const float mnew  = fmaxf(mrow[i], rm);
            const float alpha = __expf(mrow[i] - mnew);
            float rs = 0.f;
            #pragma unroll
            for (int j=0;j<4;j++){
                float p = __expf(sc[i][j] - mnew);
                sc[i][j] = p; rs += p;
            }
            #pragma unroll
            for (int msk=1; msk<16; msk<<=1) rs += __shfl_xor(rs, msk);
            lsum[i] = lsum[i]*alpha + rs;
            mrow[i] = mnew;
            #pragma unroll
            for (int j=0;j<4;j++) Oacc[i][j] *= alpha;
        }

        // write P transposed [c][r]
        #pragma unroll
        for (int i=0;i<4;i++)
            #pragma unroll
            for (int j=0;j<4;j++)
                Pst[(tx<<2)+j][(ty<<2)+i] = sc[i][j];
        __syncthreads();

        // ---- O += P V ----
        for (int cc=0; cc<64; cc++){
            float4 a4 = *(const float4*)&Pst[cc][ty<<2];
            float4 b4 = *(const float4*)&Vs[cc][tx<<2];
            float a[4] = {a4.x,a4.y,a4.z,a4.w};
            float b[4] = {b4.x,b4.y,b4.z,b4.w};
            #pragma unroll
            for (int i=0;i<4;i++)
                #pragma unroll
                for (int j=0;j<4;j++) Oacc[i][j] = fmaf(a[i], b[j], Oacc[i][j]);
        }
    }

    // epilogue: O /= l, store head-major
    #pragma unroll
    for (int i=0;i<4;i++){
        const float inv = 1.0f / lsum[i];
        float4 o = {Oacc[i][0]*inv, Oacc[i][1]*inv, Oacc[i][2]*inv, Oacc[i][3]*inv};
        *(float4*)&ob[((size_t)bh*SEQ + (size_t)qt*64 + (ty<<2)+i)*DKH + (tx<<2)] = o;
    }
}

// ---------------------------------------------------------------------------
// Kernel C: output projection. out[m,d] = sum_e AO[m,e] * Wo[d,e], where
// AO[m,e] is gathered from the head-major attention buffer.
// ---------------------------------------------------------------------------
__global__ __launch_bounds__(256)
void outproj_kernel(const float* __restrict__ ao,   // [bh][s][c]
                    const float* __restrict__ Wo,
                    float* __restrict__ out)        // [m][d]
{
    __shared__ float As[16][68];
    __shared__ float Bs[16][68];

    const int t    = threadIdx.x;
    const int m0   = blockIdx.x * 64;
    const int n0   = blockIdx.y * 64;
    const int tx   = t & 15, ty = t >> 4;
    const int lrow = t >> 2;
    const int lk4  = (t & 3) << 2;

    const int m = m0 + lrow;
    const int b = m >> 11;
    const int s = m & 2047;

    float acc[4][4];
    #pragma unroll
    for (int i=0;i<4;i++)
        #pragma unroll
        for (int j=0;j<4;j++) acc[i][j]=0.f;

    const float* wp = Wo + (size_t)(n0 + lrow)*D_MODEL + lk4;

    for (int k0 = 0; k0 < D_MODEL; k0 += 16) {
        const int e = k0 + lk4;
        const int h = e >> 6;
        const int c = e & 63;
        float4 xa = *(const float4*)&ao[(((size_t)(b*NHEAD + h))*SEQ + s)*DKH + c];
        float4 wb = *(const float4*)(wp + k0);
        As[lk4+0][lrow]=xa.x; As[lk4+1][lrow]=xa.y; As[lk4+2][lrow]=xa.z; As[lk4+3][lrow]=xa.w;
        Bs[lk4+0][lrow]=wb.x; Bs[lk4+1][lrow]=wb.y; Bs[lk4+2][lrow]=wb.z; Bs[lk4+3][lrow]=wb.w;
        __syncthreads();
        #pragma unroll
        for (int kk=0;kk<16;kk++){
            float4 a4 = *(const float4*)&As[kk][ty<<2];
            float4 b4 = *(const float4*)&Bs[kk][tx<<2];
            float a[4] = {a4.x,a4.y,a4.z,a4.w};
            float bb[4] = {b4.x,b4.y,b4.z,b4.w};
            #pragma unroll
            for (int i=0;i<4;i++)
                #pragma unroll
                for (int j=0;j<4;j++) acc[i][j] = fmaf(a[i], bb[j], acc[i][j]);
        }
        __syncthreads();
    }

    #pragma unroll
    for (int i=0;i<4;i++){
        float4 o = {acc[i][0],acc[i][1],acc[i][2],acc[i][3]};
        *(float4*)&out[(size_t)(m0 + (ty<<2) + i)*D_MODEL + n0 + (tx<<2)] = o;
    }
}

// ---------------------------------------------------------------------------
extern "C" void kernel_launch(void* const* d_in, const int* in_sizes, int n_in,
                              void* d_out, int out_size, void* d_ws, size_t ws_size,
                              hipStream_t stream)
{
    (void)in_sizes; (void)n_in; (void)out_size; (void)ws_size;
    const float* x   = (const float*)d_in[0];
    const int*   pos = (const int*)  d_in[1];
    const float* Wq  = (const float*)d_in[2];
    const float* Wk  = (const float*)d_in[3];
    const float* Wv  = (const float*)d_in[4];
    const float* Wo  = (const float*)d_in[5];
    float* out = (float*)d_out;

    const size_t per = (size_t)BH*SEQ*DKH;   // 8M floats = 32 MB
    float* qb = (float*)d_ws;
    float* kb = qb + per;
    float* vb = kb + per;
    // attention output overwrites qb (each flash block reads only its own Q rows)
    float* ao = qb;

    dim3 gA(MROWS/64, D_MODEL/64, 3);
    qkv_rope_kernel<<<gA, 256, 0, stream>>>(x, pos, Wq, Wk, Wv, qb, kb, vb);

    dim3 gB(SEQ/64, BH);
    flash_kernel<<<gB, 256, 0, stream>>>(qb, kb, vb, ao);

    dim3 gC(MROWS/64, D_MODEL/64);
    outproj_kernel<<<gC, 256, 0, stream>>>(ao, Wo, out);
}

// Round 2
// 1272.343 us; speedup vs baseline: 1.7700x; 1.7700x over previous
//
#include <hip/hip_runtime.h>
#include <hip/hip_bf16.h>
#include <math.h>

#define D_MODEL 1024
#define NHEAD   16
#define DKH     64
#define BATCH   4
#define SEQ     2048
#define BH      (BATCH*NHEAD)    // 64
#define MROWS   (BATCH*SEQ)      // 8192

typedef __attribute__((ext_vector_type(8))) short bf16x8;
typedef __attribute__((ext_vector_type(4))) short bf16x4;
typedef __attribute__((ext_vector_type(4))) float f32x4;

__device__ __forceinline__ short f2bf(float x){
    union { float f; unsigned u; } v; v.f = x;
    unsigned r = (v.u + 0x7fffu + ((v.u >> 16) & 1u)) >> 16;
    return (short)r;
}
__device__ __forceinline__ float bf2f(short s){
    union { unsigned u; float f; } v; v.u = ((unsigned)(unsigned short)s) << 16; return v.f;
}
__device__ __forceinline__ f32x4 mfma16(bf16x8 a, bf16x8 b, f32x4 c){
    return __builtin_amdgcn_mfma_f32_16x16x32_bf16(a, b, c, 0, 0, 0);
}

// ---------------------------------------------------------------------------
// Kernel A: fused QKV projection + RoPE on Q,K (fp32 vector GEMM, unchanged).
// Output head-major: out[bh][s][c].
// ---------------------------------------------------------------------------
__global__ __launch_bounds__(256)
void qkv_rope_kernel(const float* __restrict__ x,
                     const int*   __restrict__ pos,
                     const float* __restrict__ Wq,
                     const float* __restrict__ Wk,
                     const float* __restrict__ Wv,
                     float* __restrict__ qb,
                     float* __restrict__ kb,
                     float* __restrict__ vb)
{
    const int which = blockIdx.z;
    const float* __restrict__ W    = (which==0) ? Wq : (which==1) ? Wk : Wv;
    float*       __restrict__ outb = (which==0) ? qb : (which==1) ? kb : vb;

    __shared__ float As[16][68];
    __shared__ float Bs[16][68];

    const int t    = threadIdx.x;
    const int m0   = blockIdx.x * 64;
    const int n0   = blockIdx.y * 64;
    const int tx   = t & 15, ty = t >> 4;
    const int lrow = t >> 2;
    const int lk4  = (t & 3) << 2;

    float acc[4][4];
    #pragma unroll
    for (int i=0;i<4;i++)
        #pragma unroll
        for (int j=0;j<4;j++) acc[i][j]=0.f;

    const float* xp = x + (size_t)(m0 + lrow)*D_MODEL + lk4;
    const float* wp = W + (size_t)(n0 + lrow)*D_MODEL + lk4;

    for (int k0 = 0; k0 < D_MODEL; k0 += 16) {
        float4 xa = *(const float4*)(xp + k0);
        float4 wb = *(const float4*)(wp + k0);
        As[lk4+0][lrow]=xa.x; As[lk4+1][lrow]=xa.y; As[lk4+2][lrow]=xa.z; As[lk4+3][lrow]=xa.w;
        Bs[lk4+0][lrow]=wb.x; Bs[lk4+1][lrow]=wb.y; Bs[lk4+2][lrow]=wb.z; Bs[lk4+3][lrow]=wb.w;
        __syncthreads();
        #pragma unroll
        for (int kk=0;kk<16;kk++){
            float4 a4 = *(const float4*)&As[kk][ty<<2];
            float4 b4 = *(const float4*)&Bs[kk][tx<<2];
            float a[4] = {a4.x,a4.y,a4.z,a4.w};
            float b[4] = {b4.x,b4.y,b4.z,b4.w};
            #pragma unroll
            for (int i=0;i<4;i++)
                #pragma unroll
                for (int j=0;j<4;j++) acc[i][j] = fmaf(a[i], b[j], acc[i][j]);
        }
        __syncthreads();
    }

    const int d0 = n0 + (tx<<2);
    const int h  = d0 >> 6;
    const int c0 = d0 & 63;
    #pragma unroll
    for (int i=0;i<4;i++){
        const int m = m0 + (ty<<2) + i;
        const int b = m >> 11;
        const int s = m & 2047;
        float o0 = acc[i][0], o1 = acc[i][1], o2 = acc[i][2], o3 = acc[i][3];
        if (which < 2) {
            const float p = (float)pos[s];
            {
                const int   jj  = c0 >> 1;
                const float invf = powf(10000.0f, -(float)jj * (1.0f/32.0f));
                const float ang  = p * invf;
                float sn, cs; sincosf(ang, &sn, &cs);
                float xe = o0, xo = o1;
                o0 = xe*cs - xo*sn;
                o1 = xe*sn + xo*cs;
            }
            {
                const int   jj  = (c0 >> 1) + 1;
                const float invf = powf(10000.0f, -(float)jj * (1.0f/32.0f));
                const float ang  = p * invf;
                float sn, cs; sincosf(ang, &sn, &cs);
                float xe = o2, xo = o3;
                o2 = xe*cs - xo*sn;
                o3 = xe*sn + xo*cs;
            }
        }
        float4 ov = {o0,o1,o2,o3};
        *(float4*)&outb[(((size_t)(b*NHEAD + h))*SEQ + s)*DKH + c0] = ov;
    }
}

// ---------------------------------------------------------------------------
// Kernel B: causal flash attention via bf16-split MFMA.
//  - block = 256 threads = 4 waves; Q tile = 128 rows (wave = 32 rows); K tile = 64.
//  - Q frags in registers (hi/lo, scaled by 1/8) for whole block.
//  - K, V^T staged in LDS as bf16 hi/lo with XOR swizzle ^((row&7)<<3) (shorts).
//  - Swapped QK^T: S^T = mfma(K, Q) -> lane owns q-row = lane&15, c = g*4+reg.
//  - Split product: 3 MFMAs (Ah*Bh + Ah*Bl + Al*Bh) per logical MFMA.
//  - Online softmax; P packed hi/lo into per-wave LDS (b64 stores), re-read as
//    swizzled b128 A-frags for PV.
// ---------------------------------------------------------------------------
__global__ __launch_bounds__(256)
void flash_mfma_kernel(const float* __restrict__ qb,
                       const float* __restrict__ kb,
                       const float* __restrict__ vb,
                       float* __restrict__ ob)
{
    const int qt = (int)(gridDim.x - 1) - (int)blockIdx.x;   // big tiles first
    const int bh = blockIdx.y;
    const int t  = threadIdx.x;
    const int w  = t >> 6;
    const int l  = t & 63;
    const int ln = l & 15;
    const int g  = l >> 4;

    __shared__ short lKhi[4096], lKlo[4096];     // [c=64][k=64]
    __shared__ short lVhi[4096], lVlo[4096];     // [d=64][c=64] (V transposed)
    __shared__ short lPhi[4][2048], lPlo[4][2048]; // per-wave [r=32][c=64]

    const int swz = (ln & 7) << 3;   // swizzle (short units) — row&7 == ln&7 for all frag rows

    // ---- Q fragments in registers (hi/lo), scaled by 1/sqrt(dk)=1/8 ----
    bf16x8 qh[2][2], ql[2][2];    // [rt][ks]
    {
        const int qrow0 = qt*128 + w*32;
        #pragma unroll
        for (int rt=0; rt<2; rt++){
            #pragma unroll
            for (int ks=0; ks<2; ks++){
                const float* qp = qb + ((size_t)bh*SEQ + qrow0 + rt*16 + ln)*DKH + ks*32 + g*8;
                float4 x0 = *(const float4*)qp;
                float4 x1 = *(const float4*)(qp+4);
                float xs[8] = {x0.x,x0.y,x0.z,x0.w,x1.x,x1.y,x1.z,x1.w};
                short hi[8], lo[8];
                #pragma unroll
                for (int i=0;i<8;i++){
                    float v = xs[i]*0.125f;
                    hi[i] = f2bf(v);
                    lo[i] = f2bf(v - bf2f(hi[i]));
                }
                qh[rt][ks] = (bf16x8){hi[0],hi[1],hi[2],hi[3],hi[4],hi[5],hi[6],hi[7]};
                ql[rt][ks] = (bf16x8){lo[0],lo[1],lo[2],lo[3],lo[4],lo[5],lo[6],lo[7]};
            }
        }
    }

    f32x4 oacc[2][4];
    #pragma unroll
    for (int rt=0; rt<2; rt++)
        #pragma unroll
        for (int dm=0; dm<4; dm++)
            oacc[rt][dm] = (f32x4){0.f,0.f,0.f,0.f};
    float m_run[2] = {-3.0e38f, -3.0e38f};
    float l_run[2] = {0.f, 0.f};

    const int ktmax = 2*qt + 1;
    for (int kt = 0; kt <= ktmax; ++kt){
        __syncthreads();   // prior iter's LDS readers done

        // ---- stage K tile (hi/lo), fully-coalesced loads ----
        #pragma unroll
        for (int rep=0; rep<4; rep++){
            int idx = t + rep*256;          // float4 index in 64x64 tile
            int row = idx >> 4;             // c
            int kc  = (idx & 15) << 2;      // k base
            float4 kx = *(const float4*)&kb[((size_t)bh*SEQ + kt*64 + row)*DKH + kc];
            float xs[4] = {kx.x,kx.y,kx.z,kx.w};
            short hi[4], lo[4];
            #pragma unroll
            for (int i=0;i<4;i++){
                hi[i] = f2bf(xs[i]);
                lo[i] = f2bf(xs[i] - bf2f(hi[i]));
            }
            int si = (row*64 + kc) ^ ((row&7)<<3);
            *(bf16x4*)&lKhi[si] = (bf16x4){hi[0],hi[1],hi[2],hi[3]};
            *(bf16x4*)&lKlo[si] = (bf16x4){lo[0],lo[1],lo[2],lo[3]};
        }
        // ---- stage V^T tile (hi/lo): thread owns d = t&63, c chunk of 16 ----
        {
            int d  = t & 63;
            int c0 = (t >> 6) << 4;
            const float* vcol = vb + ((size_t)bh*SEQ + kt*64 + c0)*DKH + d;
            float vvf[16];
            #pragma unroll
            for (int j=0;j<16;j++) vvf[j] = vcol[(size_t)j*DKH];
            short hh[16], ll[16];
            #pragma unroll
            for (int j=0;j<16;j++){
                hh[j] = f2bf(vvf[j]);
                ll[j] = f2bf(vvf[j] - bf2f(hh[j]));
            }
            int si0 = (d*64 + c0)     ^ ((d&7)<<3);
            int si1 = (d*64 + c0 + 8) ^ ((d&7)<<3);
            *(bf16x8*)&lVhi[si0] = (bf16x8){hh[0],hh[1],hh[2],hh[3],hh[4],hh[5],hh[6],hh[7]};
            *(bf16x8*)&lVhi[si1] = (bf16x8){hh[8],hh[9],hh[10],hh[11],hh[12],hh[13],hh[14],hh[15]};
            *(bf16x8*)&lVlo[si0] = (bf16x8){ll[0],ll[1],ll[2],ll[3],ll[4],ll[5],ll[6],ll[7]};
            *(bf16x8*)&lVlo[si1] = (bf16x8){ll[8],ll[9],ll[10],ll[11],ll[12],ll[13],ll[14],ll[15]};
        }
        __syncthreads();

        // wave fully above diagonal for this K tile? (all masked)
        if (kt*64 > qt*128 + w*32 + 31) continue;

        // ---- QK^T (swapped): s[cm][rn] holds S^T tile (c rows, r cols) ----
        f32x4 s[4][2];
        #pragma unroll
        for (int cm=0; cm<4; cm++)
            #pragma unroll
            for (int rn=0; rn<2; rn++)
                s[cm][rn] = (f32x4){0.f,0.f,0.f,0.f};

        #pragma unroll
        for (int ks=0; ks<2; ks++){
            #pragma unroll
            for (int cm=0; cm<4; cm++){
                int si = ((cm*16 + ln)*64 + ks*32 + g*8) ^ swz;
                bf16x8 ah = *(const bf16x8*)&lKhi[si];
                bf16x8 al = *(const bf16x8*)&lKlo[si];
                #pragma unroll
                for (int rn=0; rn<2; rn++){
                    s[cm][rn] = mfma16(ah, qh[rn][ks], s[cm][rn]);
                    s[cm][rn] = mfma16(ah, ql[rn][ks], s[cm][rn]);
                    s[cm][rn] = mfma16(al, qh[rn][ks], s[cm][rn]);
                }
            }
        }

        // ---- causal mask (only tiles that touch the diagonal) ----
        if (kt*64 + 63 > qt*128 + w*32){
            #pragma unroll
            for (int cm=0; cm<4; cm++){
                #pragma unroll
                for (int rn=0; rn<2; rn++){
                    #pragma unroll
                    for (int r=0; r<4; r++){
                        int cg = kt*64 + cm*16 + g*4 + r;
                        int rg = qt*128 + w*32 + rn*16 + ln;
                        if (cg > rg) s[cm][rn][r] = -3.0e38f;
                    }
                }
            }
        }

        // ---- online softmax (lane owns q-row ln per rn) ----
        float alpha[2];
        #pragma unroll
        for (int rn=0; rn<2; rn++){
            float mx = -3.0e38f;
            #pragma unroll
            for (int cm=0; cm<4; cm++)
                #pragma unroll
                for (int r=0; r<4; r++) mx = fmaxf(mx, s[cm][rn][r]);
            mx = fmaxf(mx, __shfl_xor(mx, 16));
            mx = fmaxf(mx, __shfl_xor(mx, 32));
            float mnew = fmaxf(m_run[rn], mx);
            alpha[rn] = __expf(m_run[rn] - mnew);
            m_run[rn] = mnew;
            float ls = 0.f;
            #pragma unroll
            for (int cm=0; cm<4; cm++){
                #pragma unroll
                for (int r=0; r<4; r++){
                    float p = __expf(s[cm][rn][r] - mnew);
                    s[cm][rn][r] = p;
                    ls += p;
                }
            }
            ls += __shfl_xor(ls, 16);
            ls += __shfl_xor(ls, 32);
            l_run[rn] = l_run[rn]*alpha[rn] + ls;
        }

        // ---- pack P (hi/lo) into per-wave LDS ----
        #pragma unroll
        for (int rn=0; rn<2; rn++){
            #pragma unroll
            for (int cm=0; cm<4; cm++){
                short hi[4], lo[4];
                #pragma unroll
                for (int r=0; r<4; r++){
                    float p = s[cm][rn][r];
                    hi[r] = f2bf(p);
                    lo[r] = f2bf(p - bf2f(hi[r]));
                }
                int row = rn*16 + ln;
                int si = (row*64 + cm*16 + g*4) ^ ((row&7)<<3);
                *(bf16x4*)&lPhi[w][si] = (bf16x4){hi[0],hi[1],hi[2],hi[3]};
                *(bf16x4*)&lPlo[w][si] = (bf16x4){lo[0],lo[1],lo[2],lo[3]};
            }
        }

        // ---- rescale O by alpha (broadcast to O-layout rows) ----
        #pragma unroll
        for (int rt=0; rt<2; rt++){
            #pragma unroll
            for (int r=0; r<4; r++){
                float a = __shfl(alpha[rt], g*4 + r);
                #pragma unroll
                for (int dm=0; dm<4; dm++) oacc[rt][dm][r] *= a;
            }
        }

        // ---- PV: O += P * V ----
        #pragma unroll
        for (int ks2=0; ks2<2; ks2++){
            bf16x8 ph[2], pl[2], vh[4], vl[4];
            #pragma unroll
            for (int rt=0; rt<2; rt++){
                int si = ((rt*16 + ln)*64 + ks2*32 + g*8) ^ swz;
                ph[rt] = *(const bf16x8*)&lPhi[w][si];
                pl[rt] = *(const bf16x8*)&lPlo[w][si];
            }
            #pragma unroll
            for (int dm=0; dm<4; dm++){
                int si = ((dm*16 + ln)*64 + ks2*32 + g*8) ^ swz;
                vh[dm] = *(const bf16x8*)&lVhi[si];
                vl[dm] = *(const bf16x8*)&lVlo[si];
            }
            #pragma unroll
            for (int rt=0; rt<2; rt++){
                #pragma unroll
                for (int dm=0; dm<4; dm++){
                    oacc[rt][dm] = mfma16(ph[rt], vh[dm], oacc[rt][dm]);
                    oacc[rt][dm] = mfma16(ph[rt], vl[dm], oacc[rt][dm]);
                    oacc[rt][dm] = mfma16(pl[rt], vh[dm], oacc[rt][dm]);
                }
            }
        }
    }

    // ---- epilogue: O /= l, store head-major fp32 ----
    #pragma unroll
    for (int rt=0; rt<2; rt++){
        float inv[4];
        #pragma unroll
        for (int r=0; r<4; r++) inv[r] = 1.0f / __shfl(l_run[rt], g*4 + r);
        #pragma unroll
        for (int dm=0; dm<4; dm++){
            #pragma unroll
            for (int r=0; r<4; r++){
                ob[((size_t)bh*SEQ + qt*128 + w*32 + rt*16 + g*4 + r)*DKH + dm*16 + ln]
                    = oacc[rt][dm][r] * inv[r];
            }
        }
    }
}

// ---------------------------------------------------------------------------
// Kernel C: output projection (fp32 vector GEMM, unchanged).
// ---------------------------------------------------------------------------
__global__ __launch_bounds__(256)
void outproj_kernel(const float* __restrict__ ao,
                    const float* __restrict__ Wo,
                    float* __restrict__ out)
{
    __shared__ float As[16][68];
    __shared__ float Bs[16][68];

    const int t    = threadIdx.x;
    const int m0   = blockIdx.x * 64;
    const int n0   = blockIdx.y * 64;
    const int tx   = t & 15, ty = t >> 4;
    const int lrow = t >> 2;
    const int lk4  = (t & 3) << 2;

    const int m = m0 + lrow;
    const int b = m >> 11;
    const int s = m & 2047;

    float acc[4][4];
    #pragma unroll
    for (int i=0;i<4;i++)
        #pragma unroll
        for (int j=0;j<4;j++) acc[i][j]=0.f;

    const float* wp = Wo + (size_t)(n0 + lrow)*D_MODEL + lk4;

    for (int k0 = 0; k0 < D_MODEL; k0 += 16) {
        const int e = k0 + lk4;
        const int h = e >> 6;
        const int c = e & 63;
        float4 xa = *(const float4*)&ao[(((size_t)(b*NHEAD + h))*SEQ + s)*DKH + c];
        float4 wb = *(const float4*)(wp + k0);
        As[lk4+0][lrow]=xa.x; As[lk4+1][lrow]=xa.y; As[lk4+2][lrow]=xa.z; As[lk4+3][lrow]=xa.w;
        Bs[lk4+0][lrow]=wb.x; Bs[lk4+1][lrow]=wb.y; Bs[lk4+2][lrow]=wb.z; Bs[lk4+3][lrow]=wb.w;
        __syncthreads();
        #pragma unroll
        for (int kk=0;kk<16;kk++){
            float4 a4 = *(const float4*)&As[kk][ty<<2];
            float4 b4 = *(const float4*)&Bs[kk][tx<<2];
            float a[4] = {a4.x,a4.y,a4.z,a4.w};
            float bb[4] = {b4.x,b4.y,b4.z,b4.w};
            #pragma unroll
            for (int i=0;i<4;i++)
                #pragma unroll
                for (int j=0;j<4;j++) acc[i][j] = fmaf(a[i], bb[j], acc[i][j]);
        }
        __syncthreads();
    }

    #pragma unroll
    for (int i=0;i<4;i++){
        float4 o = {acc[i][0],acc[i][1],acc[i][2],acc[i][3]};
        *(float4*)&out[(size_t)(m0 + (ty<<2) + i)*D_MODEL + n0 + (tx<<2)] = o;
    }
}

// ---------------------------------------------------------------------------
extern "C" void kernel_launch(void* const* d_in, const int* in_sizes, int n_in,
                              void* d_out, int out_size, void* d_ws, size_t ws_size,
                              hipStream_t stream)
{
    (void)in_sizes; (void)n_in; (void)out_size; (void)ws_size;
    const float* x   = (const float*)d_in[0];
    const int*   pos = (const int*)  d_in[1];
    const float* Wq  = (const float*)d_in[2];
    const float* Wk  = (const float*)d_in[3];
    const float* Wv  = (const float*)d_in[4];
    const float* Wo  = (const float*)d_in[5];
    float* out = (float*)d_out;

    const size_t per = (size_t)BH*SEQ*DKH;   // 8M floats = 32 MB
    float* qb = (float*)d_ws;
    float* kb = qb + per;
    float* vb = kb + per;
    float* ao = qb;   // attention output overwrites Q buffer (safe: each block
                      // loads its own Q rows into registers before writing)

    dim3 gA(MROWS/64, D_MODEL/64, 3);
    qkv_rope_kernel<<<gA, 256, 0, stream>>>(x, pos, Wq, Wk, Wv, qb, kb, vb);

    dim3 gB(SEQ/128, BH);
    flash_mfma_kernel<<<gB, 256, 0, stream>>>(qb, kb, vb, ao);

    dim3 gC(MROWS/64, D_MODEL/64);
    outproj_kernel<<<gC, 256, 0, stream>>>(ao, Wo, out);
}

// Round 7
// 808.322 us; speedup vs baseline: 2.7861x; 1.5741x over previous
//
#include <hip/hip_runtime.h>
#include <hip/hip_bf16.h>
#include <math.h>

#define D_MODEL 1024
#define NHEAD   16
#define DKH     64
#define BATCH   4
#define SEQ     2048
#define BH      (BATCH*NHEAD)    // 64
#define MROWS   (BATCH*SEQ)      // 8192

typedef __attribute__((ext_vector_type(8))) short bf16x8;
typedef __attribute__((ext_vector_type(4))) short bf16x4;
typedef __attribute__((ext_vector_type(4))) float f32x4;

__device__ __forceinline__ short f2bf(float x){
    union { float f; unsigned u; } v; v.f = x;
    unsigned r = (v.u + 0x7fffu + ((v.u >> 16) & 1u)) >> 16;
    return (short)r;
}
__device__ __forceinline__ float bf2f(short s){
    union { unsigned u; float f; } v; v.u = ((unsigned)(unsigned short)s) << 16; return v.f;
}
__device__ __forceinline__ unsigned fasu(float x){ union{float f;unsigned u;} v; v.f=x; return v.u; }
__device__ __forceinline__ float uasf(unsigned x){ union{unsigned u;float f;} v; v.u=x; return v.f; }
__device__ __forceinline__ f32x4 mfma16(bf16x8 a, bf16x8 b, f32x4 c){
    return __builtin_amdgcn_mfma_f32_16x16x32_bf16(a, b, c, 0, 0, 0);
}

// Dekker-style truncation split of 4 fp32 into packed bf16 hi (uint2) + lo (uint2).
// hi = trunc-to-bf16(x) (exact subtraction), lo = trunc-to-bf16(x - hi).
// 3-term MFMA (AhBh+AhBl+AlBh) then carries ~2^-17 relative error per product.
__device__ __forceinline__ void split4(float4 f, uint2* hi, uint2* lo){
    unsigned u0=fasu(f.x), u1=fasu(f.y), u2=fasu(f.z), u3=fasu(f.w);
    unsigned h0=u0&0xFFFF0000u, h1=u1&0xFFFF0000u, h2=u2&0xFFFF0000u, h3=u3&0xFFFF0000u;
    float l0=f.x-uasf(h0), l1=f.y-uasf(h1), l2=f.z-uasf(h2), l3=f.w-uasf(h3);
    hi->x = h1 | (u0>>16);
    hi->y = h3 | (u2>>16);
    unsigned v0=fasu(l0), v1=fasu(l1), v2=fasu(l2), v3=fasu(l3);
    lo->x = (v1&0xFFFF0000u) | (v0>>16);
    lo->y = (v3&0xFFFF0000u) | (v2>>16);
}

// ---------------------------------------------------------------------------
// Kernel A: QKV projection via bf16-split MFMA, convert-on-the-fly staging,
// fused RoPE epilogue (inline __sincosf). C[m,n] = sum_k X[m,k] W[n,k].
// 128x128 tile, BK=64, 4 waves (2x2 of 64x64). LDS [128][64] shorts,
// XOR swizzle ^((row&7)<<3). Writes q,k,v fp32 head-major [bh][s][c].
// ---------------------------------------------------------------------------
__global__ __launch_bounds__(256, 2)
void gemm_qkv_kernel(const float* __restrict__ x,
                     const int*   __restrict__ pos,
                     const float* __restrict__ Wq,
                     const float* __restrict__ Wk,
                     const float* __restrict__ Wv,
                     float* __restrict__ qb,
                     float* __restrict__ kb,
                     float* __restrict__ vb)
{
    const int which = blockIdx.z;
    const float* __restrict__ W    = (which==0)?Wq:(which==1)?Wk:Wv;
    float*       __restrict__ outb = (which==0)?qb:(which==1)?kb:vb;

    __shared__ short lAh[128*64], lAl[128*64], lBh[128*64], lBl[128*64];

    const int t  = threadIdx.x;
    const int w  = t >> 6, l = t & 63;
    const int ln = l & 15, g = l >> 4;
    const int wr = w >> 1, wc = w & 1;
    const int m0 = blockIdx.x * 128, n0 = blockIdx.y * 128;

    f32x4 acc[4][4];
    #pragma unroll
    for (int mi=0;mi<4;mi++)
        #pragma unroll
        for (int ni=0;ni<4;ni++) acc[mi][ni] = (f32x4){0.f,0.f,0.f,0.f};

    for (int k0 = 0; k0 < D_MODEL; k0 += 64){
        __syncthreads();
        #pragma unroll
        for (int i=0;i<8;i++){
            int c    = i*256 + t;          // float4 unit, 0..2047
            int row  = c >> 4;             // 0..127
            int col4 = (c & 15) << 2;      // 0..60
            int si   = (row*64 + col4) ^ ((row & 7) << 3);
            float4 fa = *(const float4*)&x[(size_t)(m0+row)*D_MODEL + k0 + col4];
            uint2 ah_, al_;
            split4(fa, &ah_, &al_);
            *(uint2*)&lAh[si] = ah_;
            *(uint2*)&lAl[si] = al_;
            float4 fb = *(const float4*)&W[(size_t)(n0+row)*D_MODEL + k0 + col4];
            uint2 bh_, bl_;
            split4(fb, &bh_, &bl_);
            *(uint2*)&lBh[si] = bh_;
            *(uint2*)&lBl[si] = bl_;
        }
        __syncthreads();

        #pragma unroll
        for (int ks=0; ks<2; ks++){
            bf16x8 ah[4], al[4], bh[4], bl[4];
            #pragma unroll
            for (int mi=0;mi<4;mi++){
                int row = wr*64 + mi*16 + ln;
                int si  = (row*64 + ks*32 + g*8) ^ ((row & 7) << 3);
                ah[mi] = *(const bf16x8*)&lAh[si];
                al[mi] = *(const bf16x8*)&lAl[si];
            }
            #pragma unroll
            for (int ni=0;ni<4;ni++){
                int row = wc*64 + ni*16 + ln;
                int si  = (row*64 + ks*32 + g*8) ^ ((row & 7) << 3);
                bh[ni] = *(const bf16x8*)&lBh[si];
                bl[ni] = *(const bf16x8*)&lBl[si];
            }
            #pragma unroll
            for (int mi=0;mi<4;mi++)
                #pragma unroll
                for (int ni=0;ni<4;ni++){
                    acc[mi][ni] = mfma16(ah[mi], bh[ni], acc[mi][ni]);
                    acc[mi][ni] = mfma16(ah[mi], bl[ni], acc[mi][ni]);
                    acc[mi][ni] = mfma16(al[mi], bh[ni], acc[mi][ni]);
                }
        }
    }

    // Epilogue: RoPE (q,k only) + fp32 head-major store.
    #pragma unroll
    for (int mi=0;mi<4;mi++){
        #pragma unroll
        for (int ni=0;ni<4;ni++){
            const int n  = n0 + wc*64 + ni*16 + ln;
            const int h  = n >> 6;
            const int cc = n & 63;
            float invf = 0.f;
            if (which < 2){
                const int j = cc >> 1;
                invf = __expf(-(float)j * 0.2878231366242557f);  // ln(1e4)/32
            }
            #pragma unroll
            for (int r=0;r<4;r++){
                const int m = m0 + wr*64 + mi*16 + g*4 + r;
                const int b = m >> 11;
                const int s = m & 2047;
                float v = acc[mi][ni][r];
                float p = __shfl_xor(v, 1);   // partner column n^1 (same row)
                float res;
                if (which < 2){
                    float ang = (float)pos[s] * invf;
                    float sn, cs; __sincosf(ang, &sn, &cs);
                    res = ((n & 1) == 0) ? (v*cs - p*sn) : (p*sn + v*cs);
                } else {
                    res = v;
                }
                outb[(((size_t)(b*NHEAD + h))*SEQ + s)*DKH + cc] = res;
            }
        }
    }
}

// ---------------------------------------------------------------------------
// Kernel B: causal flash attention via bf16-split MFMA (round-2 verbatim —
// measured passing at absmax 0.0078). fp32 in, fp32 ao out (over Q buffer).
// ---------------------------------------------------------------------------
__global__ __launch_bounds__(256)
void flash_mfma_kernel(const float* __restrict__ qb,
                       const float* __restrict__ kb,
                       const float* __restrict__ vb,
                       float* __restrict__ ob)
{
    const int qt = (int)(gridDim.x - 1) - (int)blockIdx.x;   // big tiles first
    const int bh = blockIdx.y;
    const int t  = threadIdx.x;
    const int w  = t >> 6;
    const int l  = t & 63;
    const int ln = l & 15;
    const int g  = l >> 4;

    __shared__ short lKhi[4096], lKlo[4096];       // [c=64][k=64]
    __shared__ short lVhi[4096], lVlo[4096];       // [d=64][c=64]
    __shared__ short lPhi[4][2048], lPlo[4][2048]; // per-wave [r=32][c=64]

    const int swz = (ln & 7) << 3;

    // Q frags (hi/lo, scaled by 1/8)
    bf16x8 qh[2][2], ql[2][2];
    {
        const int qrow0 = qt*128 + w*32;
        #pragma unroll
        for (int rt=0; rt<2; rt++){
            #pragma unroll
            for (int ks=0; ks<2; ks++){
                const float* qp = qb + ((size_t)bh*SEQ + qrow0 + rt*16 + ln)*DKH + ks*32 + g*8;
                float4 x0 = *(const float4*)qp;
                float4 x1 = *(const float4*)(qp+4);
                float xs[8] = {x0.x,x0.y,x0.z,x0.w,x1.x,x1.y,x1.z,x1.w};
                short hi[8], lo[8];
                #pragma unroll
                for (int i=0;i<8;i++){
                    float v = xs[i]*0.125f;
                    hi[i] = f2bf(v);
                    lo[i] = f2bf(v - bf2f(hi[i]));
                }
                qh[rt][ks] = (bf16x8){hi[0],hi[1],hi[2],hi[3],hi[4],hi[5],hi[6],hi[7]};
                ql[rt][ks] = (bf16x8){lo[0],lo[1],lo[2],lo[3],lo[4],lo[5],lo[6],lo[7]};
            }
        }
    }

    f32x4 oacc[2][4];
    #pragma unroll
    for (int rt=0; rt<2; rt++)
        #pragma unroll
        for (int dm=0; dm<4; dm++)
            oacc[rt][dm] = (f32x4){0.f,0.f,0.f,0.f};
    float m_run[2] = {-3.0e38f, -3.0e38f};
    float l_run[2] = {0.f, 0.f};

    const int ktmax = 2*qt + 1;
    for (int kt = 0; kt <= ktmax; ++kt){
        __syncthreads();

        // ---- stage K tile (hi/lo) ----
        #pragma unroll
        for (int rep=0; rep<4; rep++){
            int idx = t + rep*256;
            int row = idx >> 4;
            int kc  = (idx & 15) << 2;
            float4 kx = *(const float4*)&kb[((size_t)bh*SEQ + kt*64 + row)*DKH + kc];
            float xs[4] = {kx.x,kx.y,kx.z,kx.w};
            short hi[4], lo[4];
            #pragma unroll
            for (int i=0;i<4;i++){
                hi[i] = f2bf(xs[i]);
                lo[i] = f2bf(xs[i] - bf2f(hi[i]));
            }
            int si = (row*64 + kc) ^ ((row&7)<<3);
            *(bf16x4*)&lKhi[si] = (bf16x4){hi[0],hi[1],hi[2],hi[3]};
            *(bf16x4*)&lKlo[si] = (bf16x4){lo[0],lo[1],lo[2],lo[3]};
        }
        // ---- stage V^T tile (hi/lo) ----
        {
            int d  = t & 63;
            int c0 = (t >> 6) << 4;
            const float* vcol = vb + ((size_t)bh*SEQ + kt*64 + c0)*DKH + d;
            float vvf[16];
            #pragma unroll
            for (int j=0;j<16;j++) vvf[j] = vcol[(size_t)j*DKH];
            short hh[16], ll[16];
            #pragma unroll
            for (int j=0;j<16;j++){
                hh[j] = f2bf(vvf[j]);
                ll[j] = f2bf(vvf[j] - bf2f(hh[j]));
            }
            int si0 = (d*64 + c0)     ^ ((d&7)<<3);
            int si1 = (d*64 + c0 + 8) ^ ((d&7)<<3);
            *(bf16x8*)&lVhi[si0] = (bf16x8){hh[0],hh[1],hh[2],hh[3],hh[4],hh[5],hh[6],hh[7]};
            *(bf16x8*)&lVhi[si1] = (bf16x8){hh[8],hh[9],hh[10],hh[11],hh[12],hh[13],hh[14],hh[15]};
            *(bf16x8*)&lVlo[si0] = (bf16x8){ll[0],ll[1],ll[2],ll[3],ll[4],ll[5],ll[6],ll[7]};
            *(bf16x8*)&lVlo[si1] = (bf16x8){ll[8],ll[9],ll[10],ll[11],ll[12],ll[13],ll[14],ll[15]};
        }
        __syncthreads();

        if (kt*64 > qt*128 + w*32 + 31) continue;   // wave fully masked

        // ---- QK^T (swapped): s[cm][rn] = S^T ----
        f32x4 s[4][2];
        #pragma unroll
        for (int cm=0; cm<4; cm++)
            #pragma unroll
            for (int rn=0; rn<2; rn++)
                s[cm][rn] = (f32x4){0.f,0.f,0.f,0.f};

        #pragma unroll
        for (int ks=0; ks<2; ks++){
            #pragma unroll
            for (int cm=0; cm<4; cm++){
                int si = ((cm*16 + ln)*64 + ks*32 + g*8) ^ swz;
                bf16x8 ah = *(const bf16x8*)&lKhi[si];
                bf16x8 al = *(const bf16x8*)&lKlo[si];
                #pragma unroll
                for (int rn=0; rn<2; rn++){
                    s[cm][rn] = mfma16(ah, qh[rn][ks], s[cm][rn]);
                    s[cm][rn] = mfma16(ah, ql[rn][ks], s[cm][rn]);
                    s[cm][rn] = mfma16(al, qh[rn][ks], s[cm][rn]);
                }
            }
        }

        // ---- causal mask ----
        if (kt*64 + 63 > qt*128 + w*32){
            #pragma unroll
            for (int cm=0; cm<4; cm++){
                #pragma unroll
                for (int rn=0; rn<2; rn++){
                    #pragma unroll
                    for (int r=0; r<4; r++){
                        int cg = kt*64 + cm*16 + g*4 + r;
                        int rg = qt*128 + w*32 + rn*16 + ln;
                        if (cg > rg) s[cm][rn][r] = -3.0e38f;
                    }
                }
            }
        }

        // ---- online softmax ----
        float alpha[2];
        #pragma unroll
        for (int rn=0; rn<2; rn++){
            float mx = -3.0e38f;
            #pragma unroll
            for (int cm=0; cm<4; cm++)
                #pragma unroll
                for (int r=0; r<4; r++) mx = fmaxf(mx, s[cm][rn][r]);
            mx = fmaxf(mx, __shfl_xor(mx, 16));
            mx = fmaxf(mx, __shfl_xor(mx, 32));
            float mnew = fmaxf(m_run[rn], mx);
            alpha[rn] = __expf(m_run[rn] - mnew);
            m_run[rn] = mnew;
            float ls = 0.f;
            #pragma unroll
            for (int cm=0; cm<4; cm++){
                #pragma unroll
                for (int r=0; r<4; r++){
                    float p = __expf(s[cm][rn][r] - mnew);
                    s[cm][rn][r] = p;
                    ls += p;
                }
            }
            ls += __shfl_xor(ls, 16);
            ls += __shfl_xor(ls, 32);
            l_run[rn] = l_run[rn]*alpha[rn] + ls;
        }

        // ---- pack P hi/lo into per-wave LDS ----
        #pragma unroll
        for (int rn=0; rn<2; rn++){
            #pragma unroll
            for (int cm=0; cm<4; cm++){
                short hi[4], lo[4];
                #pragma unroll
                for (int r=0; r<4; r++){
                    float p = s[cm][rn][r];
                    hi[r] = f2bf(p);
                    lo[r] = f2bf(p - bf2f(hi[r]));
                }
                int row = rn*16 + ln;
                int si = (row*64 + cm*16 + g*4) ^ ((row&7)<<3);
                *(bf16x4*)&lPhi[w][si] = (bf16x4){hi[0],hi[1],hi[2],hi[3]};
                *(bf16x4*)&lPlo[w][si] = (bf16x4){lo[0],lo[1],lo[2],lo[3]};
            }
        }

        // ---- rescale O ----
        #pragma unroll
        for (int rt=0; rt<2; rt++){
            #pragma unroll
            for (int r=0; r<4; r++){
                float a = __shfl(alpha[rt], g*4 + r);
                #pragma unroll
                for (int dm=0; dm<4; dm++) oacc[rt][dm][r] *= a;
            }
        }

        // ---- PV ----
        #pragma unroll
        for (int ks2=0; ks2<2; ks2++){
            bf16x8 ph[2], pl[2], vh[4], vl[4];
            #pragma unroll
            for (int rt=0; rt<2; rt++){
                int si = ((rt*16 + ln)*64 + ks2*32 + g*8) ^ swz;
                ph[rt] = *(const bf16x8*)&lPhi[w][si];
                pl[rt] = *(const bf16x8*)&lPlo[w][si];
            }
            #pragma unroll
            for (int dm=0; dm<4; dm++){
                int si = ((dm*16 + ln)*64 + ks2*32 + g*8) ^ swz;
                vh[dm] = *(const bf16x8*)&lVhi[si];
                vl[dm] = *(const bf16x8*)&lVlo[si];
            }
            #pragma unroll
            for (int rt=0; rt<2; rt++){
                #pragma unroll
                for (int dm=0; dm<4; dm++){
                    oacc[rt][dm] = mfma16(ph[rt], vh[dm], oacc[rt][dm]);
                    oacc[rt][dm] = mfma16(ph[rt], vl[dm], oacc[rt][dm]);
                    oacc[rt][dm] = mfma16(pl[rt], vh[dm], oacc[rt][dm]);
                }
            }
        }
    }

    // ---- epilogue: O /= l, fp32 head-major store ----
    #pragma unroll
    for (int rt=0; rt<2; rt++){
        float inv[4];
        #pragma unroll
        for (int r=0; r<4; r++) inv[r] = 1.0f / __shfl(l_run[rt], g*4 + r);
        #pragma unroll
        for (int dm=0; dm<4; dm++){
            #pragma unroll
            for (int r=0; r<4; r++){
                ob[((size_t)bh*SEQ + qt*128 + w*32 + rt*16 + g*4 + r)*DKH + dm*16 + ln]
                    = oacc[rt][dm][r] * inv[r];
            }
        }
    }
}

// ---------------------------------------------------------------------------
// Kernel C: output projection via bf16-split MFMA, convert-on-the-fly staging.
// A = attention output (fp32 head-major, gathered per head-slab), B = Wo.
// ---------------------------------------------------------------------------
__global__ __launch_bounds__(256, 2)
void gemm_out_kernel(const float* __restrict__ ao,
                     const float* __restrict__ Wo,
                     float* __restrict__ out)
{
    __shared__ short lAh[128*64], lAl[128*64], lBh[128*64], lBl[128*64];

    const int t  = threadIdx.x;
    const int w  = t >> 6, l = t & 63;
    const int ln = l & 15, g = l >> 4;
    const int wr = w >> 1, wc = w & 1;
    const int m0 = blockIdx.x * 128, n0 = blockIdx.y * 128;

    f32x4 acc[4][4];
    #pragma unroll
    for (int mi=0;mi<4;mi++)
        #pragma unroll
        for (int ni=0;ni<4;ni++) acc[mi][ni] = (f32x4){0.f,0.f,0.f,0.f};

    for (int k0 = 0; k0 < D_MODEL; k0 += 64){
        const int hh = k0 >> 6;   // head index (BK == DKH)
        __syncthreads();
        #pragma unroll
        for (int i=0;i<8;i++){
            int c    = i*256 + t;
            int row  = c >> 4;
            int col4 = (c & 15) << 2;
            int si   = (row*64 + col4) ^ ((row & 7) << 3);
            const int m = m0 + row;
            const int b = m >> 11;
            const int s = m & 2047;
            float4 fa = *(const float4*)&ao[(((size_t)(b*NHEAD + hh))*SEQ + s)*DKH + col4];
            uint2 ah_, al_;
            split4(fa, &ah_, &al_);
            *(uint2*)&lAh[si] = ah_;
            *(uint2*)&lAl[si] = al_;
            float4 fb = *(const float4*)&Wo[(size_t)(n0+row)*D_MODEL + k0 + col4];
            uint2 bh_, bl_;
            split4(fb, &bh_, &bl_);
            *(uint2*)&lBh[si] = bh_;
            *(uint2*)&lBl[si] = bl_;
        }
        __syncthreads();

        #pragma unroll
        for (int ks=0; ks<2; ks++){
            bf16x8 ah[4], al[4], bh[4], bl[4];
            #pragma unroll
            for (int mi=0;mi<4;mi++){
                int row = wr*64 + mi*16 + ln;
                int si  = (row*64 + ks*32 + g*8) ^ ((row & 7) << 3);
                ah[mi] = *(const bf16x8*)&lAh[si];
                al[mi] = *(const bf16x8*)&lAl[si];
            }
            #pragma unroll
            for (int ni=0;ni<4;ni++){
                int row = wc*64 + ni*16 + ln;
                int si  = (row*64 + ks*32 + g*8) ^ ((row & 7) << 3);
                bh[ni] = *(const bf16x8*)&lBh[si];
                bl[ni] = *(const bf16x8*)&lBl[si];
            }
            #pragma unroll
            for (int mi=0;mi<4;mi++)
                #pragma unroll
                for (int ni=0;ni<4;ni++){
                    acc[mi][ni] = mfma16(ah[mi], bh[ni], acc[mi][ni]);
                    acc[mi][ni] = mfma16(ah[mi], bl[ni], acc[mi][ni]);
                    acc[mi][ni] = mfma16(al[mi], bh[ni], acc[mi][ni]);
                }
        }
    }

    #pragma unroll
    for (int mi=0;mi<4;mi++){
        #pragma unroll
        for (int ni=0;ni<4;ni++){
            const int n = n0 + wc*64 + ni*16 + ln;
            #pragma unroll
            for (int r=0;r<4;r++){
                const int m = m0 + wr*64 + mi*16 + g*4 + r;
                out[(size_t)m*D_MODEL + n] = acc[mi][ni][r];
            }
        }
    }
}

// ---------------------------------------------------------------------------
extern "C" void kernel_launch(void* const* d_in, const int* in_sizes, int n_in,
                              void* d_out, int out_size, void* d_ws, size_t ws_size,
                              hipStream_t stream)
{
    (void)in_sizes; (void)n_in; (void)out_size; (void)ws_size;
    const float* x   = (const float*)d_in[0];
    const int*   pos = (const int*)  d_in[1];
    const float* Wq  = (const float*)d_in[2];
    const float* Wk  = (const float*)d_in[3];
    const float* Wv  = (const float*)d_in[4];
    const float* Wo  = (const float*)d_in[5];
    float* out = (float*)d_out;

    // Workspace: exactly 96 MB (proven safe in rounds 1-2).
    const size_t per = (size_t)BH*SEQ*DKH;   // 8M floats = 32 MB
    float* qb = (float*)d_ws;
    float* kb = qb + per;
    float* vb = kb + per;
    float* ao = qb;   // attention output overwrites Q buffer (each flash block
                      // reads its own Q rows into registers before writing)

    dim3 gA(MROWS/128, D_MODEL/128, 3);
    gemm_qkv_kernel<<<gA, 256, 0, stream>>>(x, pos, Wq, Wk, Wv, qb, kb, vb);

    dim3 gB(SEQ/128, BH);
    flash_mfma_kernel<<<gB, 256, 0, stream>>>(qb, kb, vb, ao);

    dim3 gC(MROWS/128, D_MODEL/128);
    gemm_out_kernel<<<gC, 256, 0, stream>>>(ao, Wo, out);
}